// Round 12
// baseline (396.538 us; speedup 1.0000x reference)
//
#include <hip/hip_runtime.h>
#include <hip/hip_fp16.h>
#include <stdint.h>

#define D_IN 256
#define D_H  97
#define RST  96      // half-prec row stride for cols 0..95: 192 B = exactly 3 cache lines
#define NPB  512     // nodes per coarse bucket (shift 9); src packs in 17 bits (N <= 131072)
#define NBMAX 256    // max coarse buckets
#define CHUNK 4096   // edges per scatter WG

typedef _Float16 f16;
typedef f16   f16x2 __attribute__((ext_vector_type(2)));
typedef f16   f16x8 __attribute__((ext_vector_type(8)));
typedef float f32x4 __attribute__((ext_vector_type(4)));

// ---------- helpers ----------
__device__ __forceinline__ int load_idx(const void* p, int is64, long long pos) {
  if (is64) return (int)(((const long long*)p)[pos]);
  return ((const int*)p)[pos];
}

// Decide int64 vs int32 edge layout; also zero bcur (replaces memset dispatch).
__global__ void detect_kernel(const void* ei, long long E, int* flag,
                              int* __restrict__ bcur, int nbuck) {
  const int* p32 = (const int*)ei;
  long long stride = E / 1024; if (stride < 1) stride = 1;
  int tid = threadIdx.x;
  for (int i = tid; i <= nbuck; i += 256) bcur[i] = 0;
  int bad = 0;
  for (int s = 0; s < 4; ++s) {
    long long k = ((long long)tid * 4 + s) * stride;
    if (k < E) {
      if (p32[2 * k + 1] != 0) bad = 1;
    }
  }
  __shared__ int sh_bad;
  if (tid == 0) sh_bad = 0;
  __syncthreads();
  if (bad) atomicOr(&sh_bad, 1);
  __syncthreads();
  if (tid == 0) *flag = sh_bad ? 0 : 1;   // 1 => int64
}

// P1: chunked scatter with per-chunk bulk allocation into fixed-capacity bucket regions.
__global__ __launch_bounds__(256) void bucket_scatter_direct(
    const void* ei, const int* __restrict__ flag, int* __restrict__ bcur,
    unsigned int* __restrict__ bsd, long long E, int nbuck, int cap) {
  __shared__ unsigned int packs[CHUNK];
  __shared__ unsigned char bkts[CHUNK];
  __shared__ int hist[NBMAX];
  __shared__ int gpos[NBMAX];
  __shared__ int cur[NBMAX];
  int tid = threadIdx.x;
  if (tid < NBMAX) { hist[tid] = 0; cur[tid] = 0; }
  __syncthreads();
  int f = *flag;
  long long base = (long long)blockIdx.x * CHUNK;
  int cnt = (int)((E - base < CHUNK) ? (E - base) : CHUNK);
  #pragma unroll 4
  for (int i = tid; i < cnt; i += 256) {
    long long e = base + i;
    int s = load_idx(ei, f, e);
    int d = load_idx(ei, f, E + e);
    int b = d >> 9;
    packs[i] = ((unsigned int)(d & (NPB - 1)) << 17) | (unsigned int)s;
    bkts[i] = (unsigned char)b;
    atomicAdd(&hist[b], 1);
  }
  __syncthreads();
  if (tid < nbuck) { int h = hist[tid]; if (h) gpos[tid] = atomicAdd(&bcur[tid], h); }
  __syncthreads();
  #pragma unroll 4
  for (int i = tid; i < cnt; i += 256) {
    int b = bkts[i];
    int r = atomicAdd(&cur[b], 1);
    int idx = gpos[b] + r;
    if (idx < cap) bsd[(size_t)b * cap + idx] = packs[i];   // clamp: drop on (never-hit) overflow
  }
}

// P2: per-bucket finalize with inline bucket-scan:
// node histogram -> prefix -> row_start + dinv -> CSR scatter.
__global__ __launch_bounds__(256) void bucket_finalize(
    const unsigned int* __restrict__ bsd, const int* __restrict__ bcur,
    int* __restrict__ row_start, float* __restrict__ dinv,
    int* __restrict__ csr_src, int N, int cap, int nbuck) {
  __shared__ int sc[256];
  __shared__ int h[NPB];
  __shared__ int rs[NPB];
  __shared__ int cur[NPB];
  __shared__ int wsum[4];
  int b = blockIdx.x, tid = threadIdx.x;
  int lane = tid & 63, wid = tid >> 6;
  // inline exclusive scan of min(bcur, cap) over all buckets
  int v = (tid < nbuck) ? min(bcur[tid], cap) : 0;
  sc[tid] = v;
  h[2 * tid] = 0; h[2 * tid + 1] = 0;
  cur[2 * tid] = 0; cur[2 * tid + 1] = 0;
  __syncthreads();
  for (int o = 1; o < 256; o <<= 1) {
    int a = (tid >= o) ? sc[tid - o] : 0;
    __syncthreads();
    sc[tid] += a;
    __syncthreads();
  }
  int cnt = min(bcur[b], cap);
  int base = sc[b] - cnt;             // exclusive prefix for this bucket
  if (b == 0 && tid == 0) row_start[N] = sc[255];
  int d0 = b * cap;
  for (int i = tid; i < cnt; i += 256) atomicAdd(&h[bsd[d0 + i] >> 17], 1);
  __syncthreads();
  int a0 = h[2 * tid], a1 = h[2 * tid + 1];
  int tsum = a0 + a1;
  int incl = tsum;
  #pragma unroll
  for (int off = 1; off < 64; off <<= 1) {
    int n = __shfl_up(incl, off, 64);
    if (lane >= off) incl += n;
  }
  if (lane == 63) wsum[wid] = incl;
  __syncthreads();
  int woff = 0;
  for (int k = 0; k < wid; ++k) woff += wsum[k];
  int excl = woff + incl - tsum + base;
  rs[2 * tid] = excl;
  rs[2 * tid + 1] = excl + a0;
  int node0 = b * NPB;
  int n0 = node0 + 2 * tid, n1 = node0 + 2 * tid + 1;
  if (n0 < N) { row_start[n0] = excl;      dinv[n0] = rsqrtf((float)(a0 + 1)); }
  if (n1 < N) { row_start[n1] = excl + a0; dinv[n1] = rsqrtf((float)(a1 + 1)); }
  __syncthreads();
  for (int i = tid; i < cnt; i += 256) {
    unsigned int p = bsd[d0 + i];
    int r = p >> 17;
    int s = (int)(p & 0x1FFFFu);
    int rel = atomicAdd(&cur[r], 1);
    csr_src[rs[r] + rel] = s;
  }
}

// ---------- prep: W1 fragment-linear fp16; W2 plain fp16 [98][98]; pad biases ----------
__global__ void prep_kernel(const float* __restrict__ W1, const float* __restrict__ b1,
                            const float* __restrict__ W2, const float* __restrict__ b2,
                            f16* __restrict__ W1lin, f16* __restrict__ W2g,
                            float* __restrict__ b1p, float* __restrict__ b2p) {
  int idx = blockIdx.x * blockDim.x + threadIdx.x;
  const int n1 = 8 * 7 * 512;   // KI1=8 fragment-linear W1
  const int n2 = 98 * 98;       // W2 [k][c]
  if (idx < n1) {
    int fid = idx >> 3, hh = idx & 7;
    int lane = fid & 63, fg = fid >> 6;
    int kb = fg / 7, cg = fg % 7;
    int c = cg * 16 + (lane & 15);
    int k = kb * 32 + (lane >> 4) * 8 + hh;
    W1lin[idx] = (f16)((c < D_H && k < 256) ? W1[k * D_H + c] : 0.f);
  } else if (idx < n1 + n2) {
    int j = idx - n1; int k = j / 98, c = j % 98;
    W2g[j] = (f16)((k < D_H && c < D_H) ? W2[k * D_H + c] : 0.f);
  } else if (idx < n1 + n2 + 128) {
    int c = idx - (n1 + n2);
    b1p[c] = (c < D_H) ? b1[c] : 0.0f;
  } else if (idx < n1 + n2 + 256) {
    int c = idx - (n1 + n2 + 128);
    b2p[c] = (c < D_H) ? b2[c] : 0.0f;
  }
}

// ---------- MFMA fp16 GEMM (layer 1): no LDS, no barriers; A and B straight to registers ----------
__global__ __launch_bounds__(256) void mfma_gemm1(
    const float* __restrict__ Af, const f16* __restrict__ Wlin,
    const float* __restrict__ dinv,
    f16* __restrict__ C, __half2* __restrict__ sideC, int N) {
  const int KI = 8;
  int tid = threadIdx.x, wave = tid >> 6, lane = tid & 63;
  int row0 = blockIdx.x * 128;
  int m = lane & 15, q = lane >> 4;
  int kf = q * 8;
  int r0 = row0 + wave * 32 + m;
  int r1 = r0 + 16;
  int rr0 = (r0 < N) ? r0 : 0;
  int rr1 = (r1 < N) ? r1 : 0;
  const f16* wbase = Wlin + lane * 8;

  f16x8 a0[KI], a1[KI];
  #pragma unroll
  for (int kb = 0; kb < KI; ++kb) {
    const float* p0 = &Af[(size_t)rr0 * 256 + kb * 32 + kf];
    const float* p1 = &Af[(size_t)rr1 * 256 + kb * 32 + kf];
    float4 u0 = *(const float4*)p0, u1 = *(const float4*)(p0 + 4);
    float4 w0 = *(const float4*)p1, w1 = *(const float4*)(p1 + 4);
    f16x8 t0, t1;
    t0[0] = (f16)u0.x; t0[1] = (f16)u0.y; t0[2] = (f16)u0.z; t0[3] = (f16)u0.w;
    t0[4] = (f16)u1.x; t0[5] = (f16)u1.y; t0[6] = (f16)u1.z; t0[7] = (f16)u1.w;
    t1[0] = (f16)w0.x; t1[1] = (f16)w0.y; t1[2] = (f16)w0.z; t1[3] = (f16)w0.w;
    t1[4] = (f16)w1.x; t1[5] = (f16)w1.y; t1[6] = (f16)w1.z; t1[7] = (f16)w1.w;
    a0[kb] = t0; a1[kb] = t1;
  }

  f32x4 acc[2][7];
  #pragma unroll
  for (int mg = 0; mg < 2; ++mg)
    #pragma unroll
    for (int cg = 0; cg < 7; ++cg)
      #pragma unroll
      for (int j = 0; j < 4; ++j) acc[mg][cg][j] = 0.f;

  #pragma unroll
  for (int kb = 0; kb < KI; ++kb) {
    #pragma unroll
    for (int cg = 0; cg < 7; ++cg) {
      f16x8 b = *(const f16x8*)&wbase[(kb * 7 + cg) * 512];
      acc[0][cg] = __builtin_amdgcn_mfma_f32_16x16x32_f16(a0[kb], b, acc[0][cg], 0, 0, 0);
      acc[1][cg] = __builtin_amdgcn_mfma_f32_16x16x32_f16(a1[kb], b, acc[1][cg], 0, 0, 0);
    }
  }

  int colb = m, rq = q * 4;
  #pragma unroll
  for (int mg = 0; mg < 2; ++mg) {
    #pragma unroll
    for (int j = 0; j < 4; ++j) {
      int r = row0 + wave * 32 + mg * 16 + rq + j;
      if (r >= N) continue;
      float dv = dinv[r];
      #pragma unroll
      for (int cg = 0; cg < 7; ++cg) {
        int c = cg * 16 + colb;
        float val = acc[mg][cg][j] * dv;
        if (c < 96)       C[(size_t)r * RST + c] = (f16)val;
        else if (c == 96) sideC[r] = __floats2half2_rn(val, 0.f);
      }
    }
  }
}

// ---------- fused agg1 + GEMV(W2): gather t1 -> h (f32, in wave) -> t2 = (h@W2)*dinv ----------
// 512 thr = 8 waves = 8 nodes/block. W2 (19.2 KB fp16) staged in LDS once per block.
__global__ __launch_bounds__(512) void agg_gemv(
    const __half* __restrict__ t, const __half2* __restrict__ side,
    const int* __restrict__ csr_src, const int* __restrict__ row_start,
    const float* __restrict__ dinv, const float* __restrict__ b1p,
    const f16* __restrict__ W2g,
    f16* __restrict__ t2, __half2* __restrict__ side2, int N) {
  __shared__ f16 W2s[98 * 98];
  __shared__ float hbuf[8][98];
  int tid = threadIdx.x;
  for (int i = tid; i < 98 * 98 / 2; i += 512)
    ((f16x2*)W2s)[i] = ((const f16x2*)W2g)[i];
  __syncthreads();
  int wave = tid >> 6, lane = tid & 63;
  int node = blockIdx.x * 8 + wave;
  if (node >= N || lane >= 49) return;

  const char* gbase = (lane < 48) ? (const char*)t + lane * 4 : (const char*)side;
  unsigned gscale = (lane < 48) ? (unsigned)(RST * 2) : 4u;
  auto GATHER = [&](int j) -> float2 {
    return __half22float2(*(const __half2*)(gbase + (size_t)((unsigned)j * gscale)));
  };
  int e = row_start[node], epd = row_start[node + 1];
  float di = dinv[node];
  float2 v = GATHER(node);
  float ax = v.x, ay = v.y;
  while ((e & 3) && e < epd) {
    float2 u = GATHER(csr_src[e]);
    ax += u.x; ay += u.y; ++e;
  }
  for (; e + 8 <= epd; e += 8) {
    int4 q0 = *(const int4*)(csr_src + e);
    int4 q1 = *(const int4*)(csr_src + e + 4);
    float2 u0 = GATHER(q0.x), u1 = GATHER(q0.y), u2 = GATHER(q0.z), u3 = GATHER(q0.w);
    float2 u4 = GATHER(q1.x), u5 = GATHER(q1.y), u6 = GATHER(q1.z), u7 = GATHER(q1.w);
    ax += ((u0.x + u1.x) + (u2.x + u3.x)) + ((u4.x + u5.x) + (u6.x + u7.x));
    ay += ((u0.y + u1.y) + (u2.y + u3.y)) + ((u4.y + u5.y) + (u6.y + u7.y));
  }
  if (e + 4 <= epd) {
    int4 q0 = *(const int4*)(csr_src + e);
    float2 u0 = GATHER(q0.x), u1 = GATHER(q0.y), u2 = GATHER(q0.z), u3 = GATHER(q0.w);
    ax += (u0.x + u1.x) + (u2.x + u3.x);
    ay += (u0.y + u1.y) + (u2.y + u3.y);
    e += 4;
  }
  for (; e < epd; ++e) {
    float2 u = GATHER(csr_src[e]);
    ax += u.x; ay += u.y;
  }
  int c0 = 2 * lane;                 // lane 48 -> c0 = 96
  ax = fmaxf(ax * di + b1p[c0], 0.f);       // h[c0]
  ay = fmaxf(ay * di + b1p[c0 + 1], 0.f);   // h[c0+1] (lane48: col 97, pad -> 0 bias, ok)
  hbuf[wave][c0] = ax;
  if (c0 + 1 < 98) hbuf[wave][c0 + 1] = ay;

  // GEMV: out[c] = sum_k h[k] * W2[k][c]  (k = 0..96); then * dinv[node]
  float s0 = 0.f, s1 = 0.f;
  const float* hl = hbuf[wave];
  #pragma unroll 4
  for (int k = 0; k < 96; k += 2) {
    float h0 = hl[k], h1 = hl[k + 1];
    f16x2 w0 = *(const f16x2*)&W2s[k * 98 + c0];
    f16x2 w1 = *(const f16x2*)&W2s[(k + 1) * 98 + c0];
    s0 += h0 * (float)w0[0] + h1 * (float)w1[0];
    s1 += h0 * (float)w0[1] + h1 * (float)w1[1];
  }
  {
    float h96 = hl[96];
    f16x2 w96 = *(const f16x2*)&W2s[96 * 98 + c0];
    s0 += h96 * (float)w96[0];
    s1 += h96 * (float)w96[1];
  }
  s0 *= di; s1 *= di;
  if (lane < 48) {
    *(__half2*)(&t2[(size_t)node * RST + c0]) = __floats2half2_rn(s0, s1);
  } else {
    side2[node] = __floats2half2_rn(s0, 0.f);
  }
}

// ---------- final aggregation (layer 2): gather t2 -> d_out (f32) ----------
__global__ __launch_bounds__(256) void agg_out(
    const __half* __restrict__ t, const __half2* __restrict__ side,
    const int* __restrict__ csr_src, const int* __restrict__ row_start,
    const float* __restrict__ dinv, const float* __restrict__ bias,
    float* __restrict__ outp, int N) {
  int lane = threadIdx.x & 63;
  int node = blockIdx.x * (blockDim.x >> 6) + (threadIdx.x >> 6);
  if (node >= N || lane >= 49) return;
  const char* gbase = (lane < 48) ? (const char*)t + lane * 4 : (const char*)side;
  unsigned gscale = (lane < 48) ? (unsigned)(RST * 2) : 4u;
  auto GATHER = [&](int j) -> float2 {
    return __half22float2(*(const __half2*)(gbase + (size_t)((unsigned)j * gscale)));
  };
  int e = row_start[node], epd = row_start[node + 1];
  float di = dinv[node];
  float2 v = GATHER(node);
  float ax = v.x, ay = v.y;
  while ((e & 3) && e < epd) {
    float2 u = GATHER(csr_src[e]);
    ax += u.x; ay += u.y; ++e;
  }
  for (; e + 8 <= epd; e += 8) {
    int4 q0 = *(const int4*)(csr_src + e);
    int4 q1 = *(const int4*)(csr_src + e + 4);
    float2 u0 = GATHER(q0.x), u1 = GATHER(q0.y), u2 = GATHER(q0.z), u3 = GATHER(q0.w);
    float2 u4 = GATHER(q1.x), u5 = GATHER(q1.y), u6 = GATHER(q1.z), u7 = GATHER(q1.w);
    ax += ((u0.x + u1.x) + (u2.x + u3.x)) + ((u4.x + u5.x) + (u6.x + u7.x));
    ay += ((u0.y + u1.y) + (u2.y + u3.y)) + ((u4.y + u5.y) + (u6.y + u7.y));
  }
  if (e + 4 <= epd) {
    int4 q0 = *(const int4*)(csr_src + e);
    float2 u0 = GATHER(q0.x), u1 = GATHER(q0.y), u2 = GATHER(q0.z), u3 = GATHER(q0.w);
    ax += (u0.x + u1.x) + (u2.x + u3.x);
    ay += (u0.y + u1.y) + (u2.y + u3.y);
    e += 4;
  }
  for (; e < epd; ++e) {
    float2 u = GATHER(csr_src[e]);
    ax += u.x; ay += u.y;
  }
  int c0 = 2 * lane;
  ax = ax * di + bias[c0];
  ay = ay * di + bias[c0 + 1];
  float* o = outp + (size_t)node * D_H;
  if (lane < 48) { o[c0] = ax; o[c0 + 1] = ay; }
  else           o[96] = ax;
}

// ---------- launch ----------
extern "C" void kernel_launch(void* const* d_in, const int* in_sizes, int n_in,
                              void* d_out, int out_size, void* d_ws, size_t ws_size,
                              hipStream_t stream) {
  const float* x  = (const float*)d_in[0];
  const void*  ei = d_in[1];
  const float* W1 = (const float*)d_in[2];
  const float* b1 = (const float*)d_in[3];
  const float* W2 = (const float*)d_in[4];
  const float* b2 = (const float*)d_in[5];
  int N = in_sizes[0] / D_IN;
  long long E = (long long)in_sizes[1] / 2;
  int nbuck = (N + NPB - 1) / NPB;
  int cap = (int)(E / nbuck) + 8192;   // uniform-random slack >> 6 sigma

  char* base = (char*)d_ws;
  size_t off = 0;
  auto alloc = [&](size_t bytes) -> void* {
    void* p = base + off;
    off = (off + bytes + 255) & ~(size_t)255;
    return p;
  };
  int*    flag      = (int*)alloc(4);
  float*  dinv      = (float*)alloc((size_t)N * 4);
  int*    row_start = (int*)alloc((size_t)(N + 1) * 4);
  int*    bcur      = (int*)alloc((size_t)(nbuck + 1) * 4);
  int*    csr_src   = (int*)alloc((size_t)E * 4);
  unsigned int* bsd = (unsigned int*)alloc((size_t)nbuck * cap * 4);
  f16*    W1lin     = (f16*)alloc((size_t)8 * 7 * 512 * 2);
  f16*    W2g       = (f16*)alloc((size_t)98 * 98 * 2);
  float*  b1p       = (float*)alloc(128 * 4);
  float*  b2p       = (float*)alloc(128 * 4);
  f16*    t1        = (f16*)alloc((size_t)N * RST * 2 + 256);
  __half2* sideT    = (__half2*)alloc((size_t)N * 4 + 256);
  f16*    t2        = (f16*)alloc((size_t)N * RST * 2 + 256);
  __half2* sideT2   = (__half2*)alloc((size_t)N * 4 + 256);

  detect_kernel<<<1, 256, 0, stream>>>(ei, E, flag, bcur, nbuck);
  bucket_scatter_direct<<<(int)((E + CHUNK - 1) / CHUNK), 256, 0, stream>>>(
      ei, flag, bcur, bsd, E, nbuck, cap);
  bucket_finalize<<<nbuck, 256, 0, stream>>>(bsd, bcur, row_start, dinv, csr_src, N, cap, nbuck);
  prep_kernel<<<(8 * 7 * 512 + 98 * 98 + 256 + 255) / 256, 256, 0, stream>>>(
      W1, b1, W2, b2, W1lin, W2g, b1p, b2p);
  mfma_gemm1<<<(N + 127) / 128, 256, 0, stream>>>(x, W1lin, dinv, t1, sideT, N);
  agg_gemv<<<(N + 7) / 8, 512, 0, stream>>>(
      (const __half*)t1, sideT, csr_src, row_start, dinv, b1p, W2g, t2, sideT2, N);
  agg_out<<<(N + 3) / 4, 256, 0, stream>>>(
      (const __half*)t2, sideT2, csr_src, row_start, dinv, b2p, (float*)d_out, N);
}

// Round 13
// 353.775 us; speedup vs baseline: 1.1209x; 1.1209x over previous
//
#include <hip/hip_runtime.h>
#include <hip/hip_fp16.h>
#include <stdint.h>

#define D_IN 256
#define D_H  97
#define RST  96      // half-prec row stride for cols 0..95: 192 B = exactly 3 cache lines
#define NPB  512     // nodes per coarse bucket (shift 9); src packs in 17 bits (N <= 131072)
#define NBMAX 256    // max coarse buckets
#define CHUNK 4096   // edges per scatter WG

typedef _Float16 f16;
typedef f16   f16x8 __attribute__((ext_vector_type(8)));
typedef float f32x4 __attribute__((ext_vector_type(4)));

// ---------- helpers ----------
__device__ __forceinline__ int load_idx(const void* p, int is64, long long pos) {
  if (is64) return (int)(((const long long*)p)[pos]);
  return ((const int*)p)[pos];
}

// Decide int64 vs int32 edge layout; also zero bcur (replaces memset dispatch).
__global__ void detect_kernel(const void* ei, long long E, int* flag,
                              int* __restrict__ bcur, int nbuck) {
  const int* p32 = (const int*)ei;
  long long stride = E / 1024; if (stride < 1) stride = 1;
  int tid = threadIdx.x;
  for (int i = tid; i <= nbuck; i += 256) bcur[i] = 0;
  int bad = 0;
  for (int s = 0; s < 4; ++s) {
    long long k = ((long long)tid * 4 + s) * stride;
    if (k < E) {
      if (p32[2 * k + 1] != 0) bad = 1;
    }
  }
  __shared__ int sh_bad;
  if (tid == 0) sh_bad = 0;
  __syncthreads();
  if (bad) atomicOr(&sh_bad, 1);
  __syncthreads();
  if (tid == 0) *flag = sh_bad ? 0 : 1;   // 1 => int64
}

// P1: chunked scatter with per-chunk bulk allocation into fixed-capacity bucket regions.
__global__ __launch_bounds__(256) void bucket_scatter_direct(
    const void* ei, const int* __restrict__ flag, int* __restrict__ bcur,
    unsigned int* __restrict__ bsd, long long E, int nbuck, int cap) {
  __shared__ unsigned int packs[CHUNK];
  __shared__ unsigned char bkts[CHUNK];
  __shared__ int hist[NBMAX];
  __shared__ int gpos[NBMAX];
  __shared__ int cur[NBMAX];
  int tid = threadIdx.x;
  if (tid < NBMAX) { hist[tid] = 0; cur[tid] = 0; }
  __syncthreads();
  int f = *flag;
  long long base = (long long)blockIdx.x * CHUNK;
  int cnt = (int)((E - base < CHUNK) ? (E - base) : CHUNK);
  #pragma unroll 4
  for (int i = tid; i < cnt; i += 256) {
    long long e = base + i;
    int s = load_idx(ei, f, e);
    int d = load_idx(ei, f, E + e);
    int b = d >> 9;
    packs[i] = ((unsigned int)(d & (NPB - 1)) << 17) | (unsigned int)s;
    bkts[i] = (unsigned char)b;
    atomicAdd(&hist[b], 1);
  }
  __syncthreads();
  if (tid < nbuck) { int h = hist[tid]; if (h) gpos[tid] = atomicAdd(&bcur[tid], h); }
  __syncthreads();
  #pragma unroll 4
  for (int i = tid; i < cnt; i += 256) {
    int b = bkts[i];
    int r = atomicAdd(&cur[b], 1);
    int idx = gpos[b] + r;
    if (idx < cap) bsd[(size_t)b * cap + idx] = packs[i];   // clamp: drop on (never-hit) overflow
  }
}

// P2: per-bucket finalize with inline bucket-scan:
// node histogram -> prefix -> row_start + dinv -> CSR scatter.
__global__ __launch_bounds__(256) void bucket_finalize(
    const unsigned int* __restrict__ bsd, const int* __restrict__ bcur,
    int* __restrict__ row_start, float* __restrict__ dinv,
    int* __restrict__ csr_src, int N, int cap, int nbuck) {
  __shared__ int sc[256];
  __shared__ int h[NPB];
  __shared__ int rs[NPB];
  __shared__ int cur[NPB];
  __shared__ int wsum[4];
  int b = blockIdx.x, tid = threadIdx.x;
  int lane = tid & 63, wid = tid >> 6;
  int v = (tid < nbuck) ? min(bcur[tid], cap) : 0;
  sc[tid] = v;
  h[2 * tid] = 0; h[2 * tid + 1] = 0;
  cur[2 * tid] = 0; cur[2 * tid + 1] = 0;
  __syncthreads();
  for (int o = 1; o < 256; o <<= 1) {
    int a = (tid >= o) ? sc[tid - o] : 0;
    __syncthreads();
    sc[tid] += a;
    __syncthreads();
  }
  int cnt = min(bcur[b], cap);
  int base = sc[b] - cnt;             // exclusive prefix for this bucket
  if (b == 0 && tid == 0) row_start[N] = sc[255];
  int d0 = b * cap;
  for (int i = tid; i < cnt; i += 256) atomicAdd(&h[bsd[d0 + i] >> 17], 1);
  __syncthreads();
  int a0 = h[2 * tid], a1 = h[2 * tid + 1];
  int tsum = a0 + a1;
  int incl = tsum;
  #pragma unroll
  for (int off = 1; off < 64; off <<= 1) {
    int n = __shfl_up(incl, off, 64);
    if (lane >= off) incl += n;
  }
  if (lane == 63) wsum[wid] = incl;
  __syncthreads();
  int woff = 0;
  for (int k = 0; k < wid; ++k) woff += wsum[k];
  int excl = woff + incl - tsum + base;
  rs[2 * tid] = excl;
  rs[2 * tid + 1] = excl + a0;
  int node0 = b * NPB;
  int n0 = node0 + 2 * tid, n1 = node0 + 2 * tid + 1;
  if (n0 < N) { row_start[n0] = excl;      dinv[n0] = rsqrtf((float)(a0 + 1)); }
  if (n1 < N) { row_start[n1] = excl + a0; dinv[n1] = rsqrtf((float)(a1 + 1)); }
  __syncthreads();
  for (int i = tid; i < cnt; i += 256) {
    unsigned int p = bsd[d0 + i];
    int r = p >> 17;
    int s = (int)(p & 0x1FFFFu);
    int rel = atomicAdd(&cur[r], 1);
    csr_src[rs[r] + rel] = s;
  }
}

// ---------- prep: pack W1/W2 into fragment-linear fp16 layout + pad biases ----------
// For fragment (kb,cg), lane l (m=l&15, q=l>>4) holds B[c=cg*16+m][k=kb*32+q*8+h], h=0..7,
// stored at Wlin[(kb*7+cg)*512 + l*8 + h]  => each wave B-load is one coalesced 1KB read.
__global__ void prep_kernel(const float* __restrict__ W1, const float* __restrict__ b1,
                            const float* __restrict__ W2, const float* __restrict__ b2,
                            f16* __restrict__ W1lin, f16* __restrict__ W2lin,
                            float* __restrict__ b1p, float* __restrict__ b2p) {
  int idx = blockIdx.x * blockDim.x + threadIdx.x;
  const int n1 = 8 * 7 * 512;   // KI1=8
  const int n2 = 4 * 7 * 512;   // KI2=4
  if (idx < n1) {
    int fid = idx >> 3, hh = idx & 7;
    int lane = fid & 63, fg = fid >> 6;
    int kb = fg / 7, cg = fg % 7;
    int c = cg * 16 + (lane & 15);
    int k = kb * 32 + (lane >> 4) * 8 + hh;
    W1lin[idx] = (f16)((c < D_H && k < 256) ? W1[k * D_H + c] : 0.f);
  } else if (idx < n1 + n2) {
    int j = idx - n1;
    int fid = j >> 3, hh = j & 7;
    int lane = fid & 63, fg = fid >> 6;
    int kb = fg / 7, cg = fg % 7;
    int c = cg * 16 + (lane & 15);
    int k = kb * 32 + (lane >> 4) * 8 + hh;
    W2lin[j] = (f16)((c < D_H && k < D_H) ? W2[k * D_H + c] : 0.f);
  } else if (idx < n1 + n2 + 128) {
    int c = idx - (n1 + n2);
    b1p[c] = (c < D_H) ? b1[c] : 0.0f;
  } else if (idx < n1 + n2 + 256) {
    int c = idx - (n1 + n2 + 128);
    b2p[c] = (c < D_H) ? b2[c] : 0.0f;
  }
}

// ---------- MFMA fp16 GEMM: no LDS, no barriers. A and B straight to registers. ----------
// Block: 256 thr = 4 waves, 128 rows; wave w owns rows w*32..w*32+31 (2 groups of 16).
template<int KI, bool IN_HALF>
__global__ __launch_bounds__(256) void mfma_gemm(
    const float* __restrict__ Af, const f16* __restrict__ Ah,
    const __half2* __restrict__ sideA,
    const f16* __restrict__ Wlin, const float* __restrict__ dinv,
    f16* __restrict__ C, __half2* __restrict__ sideC, int N) {
  int tid = threadIdx.x, wave = tid >> 6, lane = tid & 63;
  int row0 = blockIdx.x * 128;
  int m = lane & 15, q = lane >> 4;
  int kf = q * 8;
  int r0 = row0 + wave * 32 + m;
  int r1 = r0 + 16;
  int rr0 = (r0 < N) ? r0 : 0;   // clamp: OOB rows compute garbage, discarded in epilogue
  int rr1 = (r1 < N) ? r1 : 0;
  const f16* wbase = Wlin + lane * 8;

  // preload all A fragments (independent loads -> deep memory pipeline)
  f16x8 a0[KI], a1[KI];
  #pragma unroll
  for (int kb = 0; kb < KI; ++kb) {
    if constexpr (!IN_HALF) {
      const float* p0 = &Af[(size_t)rr0 * 256 + kb * 32 + kf];
      const float* p1 = &Af[(size_t)rr1 * 256 + kb * 32 + kf];
      float4 u0 = *(const float4*)p0, u1 = *(const float4*)(p0 + 4);
      float4 w0 = *(const float4*)p1, w1 = *(const float4*)(p1 + 4);
      f16x8 t0, t1;
      t0[0] = (f16)u0.x; t0[1] = (f16)u0.y; t0[2] = (f16)u0.z; t0[3] = (f16)u0.w;
      t0[4] = (f16)u1.x; t0[5] = (f16)u1.y; t0[6] = (f16)u1.z; t0[7] = (f16)u1.w;
      t1[0] = (f16)w0.x; t1[1] = (f16)w0.y; t1[2] = (f16)w0.z; t1[3] = (f16)w0.w;
      t1[4] = (f16)w1.x; t1[5] = (f16)w1.y; t1[6] = (f16)w1.z; t1[7] = (f16)w1.w;
      a0[kb] = t0; a1[kb] = t1;
    } else {
      if (kb < KI - 1) {
        a0[kb] = *(const f16x8*)&Ah[(size_t)rr0 * RST + kb * 32 + kf];
        a1[kb] = *(const f16x8*)&Ah[(size_t)rr1 * RST + kb * 32 + kf];
      } else {
        // last k-iter: k=96 is the side column; k=97..127 are zero (W rows zero-padded too)
        f16x8 z0, z1;
        #pragma unroll
        for (int j = 0; j < 8; ++j) { z0[j] = (f16)0.f; z1[j] = (f16)0.f; }
        if (q == 0) {
          z0[0] = ((const f16*)sideA)[2 * rr0];
          z1[0] = ((const f16*)sideA)[2 * rr1];
        }
        a0[kb] = z0; a1[kb] = z1;
      }
    }
  }

  f32x4 acc[2][7];
  #pragma unroll
  for (int mg = 0; mg < 2; ++mg)
    #pragma unroll
    for (int cg = 0; cg < 7; ++cg)
      #pragma unroll
      for (int j = 0; j < 4; ++j) acc[mg][cg][j] = 0.f;

  #pragma unroll
  for (int kb = 0; kb < KI; ++kb) {
    #pragma unroll
    for (int cg = 0; cg < 7; ++cg) {
      f16x8 b = *(const f16x8*)&wbase[(kb * 7 + cg) * 512];
      acc[0][cg] = __builtin_amdgcn_mfma_f32_16x16x32_f16(a0[kb], b, acc[0][cg], 0, 0, 0);
      acc[1][cg] = __builtin_amdgcn_mfma_f32_16x16x32_f16(a1[kb], b, acc[1][cg], 0, 0, 0);
    }
  }

  // epilogue: C/D mapping col=lane&15, row=(lane>>4)*4+j
  int colb = m, rq = q * 4;
  #pragma unroll
  for (int mg = 0; mg < 2; ++mg) {
    #pragma unroll
    for (int j = 0; j < 4; ++j) {
      int r = row0 + wave * 32 + mg * 16 + rq + j;
      if (r >= N) continue;
      float dv = dinv[r];
      #pragma unroll
      for (int cg = 0; cg < 7; ++cg) {
        int c = cg * 16 + colb;
        float val = acc[mg][cg][j] * dv;
        if (c < 96)       C[(size_t)r * RST + c] = (f16)val;
        else if (c == 96) sideC[r] = __floats2half2_rn(val, 0.f);
      }
    }
  }
}

// ---------- CSR aggregation: one wave per destination node, fp16 gather, f32 accum ----------
template<bool OUT_HALF, bool DO_RELU>
__global__ __launch_bounds__(256) void agg_kernel(
    const __half* __restrict__ t, const __half2* __restrict__ side,
    const int* __restrict__ csr_src, const int* __restrict__ row_start,
    const float* __restrict__ dinv, const float* __restrict__ bias,
    void* __restrict__ outp, __half2* __restrict__ side_out, int N) {
  int lane = threadIdx.x & 63;
  int node = blockIdx.x * (blockDim.x >> 6) + (threadIdx.x >> 6);
  if (node >= N || lane >= 49) return;
  const char* gbase = (lane < 48) ? (const char*)t + lane * 4 : (const char*)side;
  unsigned gscale = (lane < 48) ? (unsigned)(RST * 2) : 4u;
  auto GATHER = [&](int j) -> float2 {
    return __half22float2(*(const __half2*)(gbase + (size_t)((unsigned)j * gscale)));
  };
  int s = row_start[node], epd = row_start[node + 1];
  float di = dinv[node];
  float2 v = GATHER(node);           // self term (already x dinv[node])
  float ax = v.x, ay = v.y;
  int e = s;
  while ((e & 3) && e < epd) {
    float2 u = GATHER(csr_src[e]);
    ax += u.x; ay += u.y; ++e;
  }
  for (; e + 8 <= epd; e += 8) {
    int4 q0 = *(const int4*)(csr_src + e);
    int4 q1 = *(const int4*)(csr_src + e + 4);
    float2 u0 = GATHER(q0.x), u1 = GATHER(q0.y), u2 = GATHER(q0.z), u3 = GATHER(q0.w);
    float2 u4 = GATHER(q1.x), u5 = GATHER(q1.y), u6 = GATHER(q1.z), u7 = GATHER(q1.w);
    ax += ((u0.x + u1.x) + (u2.x + u3.x)) + ((u4.x + u5.x) + (u6.x + u7.x));
    ay += ((u0.y + u1.y) + (u2.y + u3.y)) + ((u4.y + u5.y) + (u6.y + u7.y));
  }
  if (e + 4 <= epd) {
    int4 q0 = *(const int4*)(csr_src + e);
    float2 u0 = GATHER(q0.x), u1 = GATHER(q0.y), u2 = GATHER(q0.z), u3 = GATHER(q0.w);
    ax += (u0.x + u1.x) + (u2.x + u3.x);
    ay += (u0.y + u1.y) + (u2.y + u3.y);
    e += 4;
  }
  for (; e < epd; ++e) {
    float2 u = GATHER(csr_src[e]);
    ax += u.x; ay += u.y;
  }
  int c0 = 2 * lane;                 // lane 48 -> c0 = 96
  ax = ax * di + bias[c0];
  ay = ay * di + bias[c0 + 1];
  if (DO_RELU) { ax = fmaxf(ax, 0.f); ay = fmaxf(ay, 0.f); }
  if (OUT_HALF) {
    if (lane < 48) ((__half2*)((__half*)outp + (size_t)node * RST))[lane] = __floats2half2_rn(ax, ay);
    else           side_out[node] = __floats2half2_rn(ax, 0.f);
  } else {
    float* o = (float*)outp + (size_t)node * D_H;
    if (lane < 48) { o[c0] = ax; o[c0 + 1] = ay; }
    else           o[96] = ax;
  }
}

// ---------- launch ----------
extern "C" void kernel_launch(void* const* d_in, const int* in_sizes, int n_in,
                              void* d_out, int out_size, void* d_ws, size_t ws_size,
                              hipStream_t stream) {
  const float* x  = (const float*)d_in[0];
  const void*  ei = d_in[1];
  const float* W1 = (const float*)d_in[2];
  const float* b1 = (const float*)d_in[3];
  const float* W2 = (const float*)d_in[4];
  const float* b2 = (const float*)d_in[5];
  int N = in_sizes[0] / D_IN;
  long long E = (long long)in_sizes[1] / 2;
  int nbuck = (N + NPB - 1) / NPB;
  int cap = (int)(E / nbuck) + 8192;   // uniform-random slack >> 6 sigma

  char* base = (char*)d_ws;
  size_t off = 0;
  auto alloc = [&](size_t bytes) -> void* {
    void* p = base + off;
    off = (off + bytes + 255) & ~(size_t)255;
    return p;
  };
  int*    flag      = (int*)alloc(4);
  float*  dinv      = (float*)alloc((size_t)N * 4);
  int*    row_start = (int*)alloc((size_t)(N + 1) * 4);
  int*    bcur      = (int*)alloc((size_t)(nbuck + 1) * 4);
  int*    csr_src   = (int*)alloc((size_t)E * 4);
  unsigned int* bsd = (unsigned int*)alloc((size_t)nbuck * cap * 4);
  f16*    W1lin     = (f16*)alloc((size_t)8 * 7 * 512 * 2);
  f16*    W2lin     = (f16*)alloc((size_t)4 * 7 * 512 * 2);
  float*  b1p       = (float*)alloc(128 * 4);
  float*  b2p       = (float*)alloc(128 * 4);
  f16*    t1        = (f16*)alloc((size_t)N * RST * 2 + 256);
  __half2* sideT    = (__half2*)alloc((size_t)N * 4 + 256);
  f16*    h1        = (f16*)alloc((size_t)N * RST * 2 + 256);
  __half2* sideH    = (__half2*)alloc((size_t)N * 4 + 256);

  detect_kernel<<<1, 256, 0, stream>>>(ei, E, flag, bcur, nbuck);
  bucket_scatter_direct<<<(int)((E + CHUNK - 1) / CHUNK), 256, 0, stream>>>(
      ei, flag, bcur, bsd, E, nbuck, cap);
  bucket_finalize<<<nbuck, 256, 0, stream>>>(bsd, bcur, row_start, dinv, csr_src, N, cap, nbuck);
  prep_kernel<<<(8 * 7 * 512 + 4 * 7 * 512 + 256 + 255) / 256, 256, 0, stream>>>(
      W1, b1, W2, b2, W1lin, W2lin, b1p, b2p);

  int gGemm = (N + 127) / 128;

  mfma_gemm<8, false><<<gGemm, 256, 0, stream>>>(
      x, nullptr, nullptr, W1lin, dinv, t1, sideT, N);
  agg_kernel<true, true><<<(N + 3) / 4, 256, 0, stream>>>(
      (const __half*)t1, sideT, csr_src, row_start, dinv, b1p, h1, sideH, N);
  mfma_gemm<4, true><<<gGemm, 256, 0, stream>>>(
      nullptr, h1, sideH, W2lin, dinv, t1, sideT, N);
  agg_kernel<false, false><<<(N + 3) / 4, 256, 0, stream>>>(
      (const __half*)t1, sideT, csr_src, row_start, dinv, b2p, d_out, nullptr, N);
}

// Round 14
// 352.651 us; speedup vs baseline: 1.1245x; 1.0032x over previous
//
#include <hip/hip_runtime.h>
#include <hip/hip_fp16.h>
#include <stdint.h>

#define D_IN 256
#define D_H  97
#define RST  96      // half-prec row stride for cols 0..95: 192 B = exactly 3 cache lines
#define NPB  512     // nodes per coarse bucket (shift 9); src packs in 17 bits (N <= 131072)
#define NBMAX 256    // max coarse buckets
#define CHUNK 4096   // edges per scatter WG

typedef _Float16 f16;
typedef f16   f16x8 __attribute__((ext_vector_type(8)));
typedef float f32x4 __attribute__((ext_vector_type(4)));

// ---------- helpers ----------
__device__ __forceinline__ int load_idx(const void* p, int is64, long long pos) {
  if (is64) return (int)(((const long long*)p)[pos]);
  return ((const int*)p)[pos];
}

// ---------- Kernel A: detect (block 0) || prep (blocks 1..) ----------
// detect: int64-vs-int32 edge layout probe + zero bcur.
// prep: pack W1/W2 into fragment-linear fp16 (B-fragment of (kb,cg) at lane*8), pad biases.
__global__ __launch_bounds__(256) void detect_prep(
    const void* ei, long long E, int* flag, int* __restrict__ bcur, int nbuck,
    const float* __restrict__ W1, const float* __restrict__ b1,
    const float* __restrict__ W2, const float* __restrict__ b2,
    f16* __restrict__ W1lin, f16* __restrict__ W2lin,
    float* __restrict__ b1p, float* __restrict__ b2p) {
  int tid = threadIdx.x;
  if (blockIdx.x == 0) {
    const int* p32 = (const int*)ei;
    long long stride = E / 1024; if (stride < 1) stride = 1;
    for (int i = tid; i <= nbuck; i += 256) bcur[i] = 0;
    int bad = 0;
    for (int s = 0; s < 4; ++s) {
      long long k = ((long long)tid * 4 + s) * stride;
      if (k < E) {
        if (p32[2 * k + 1] != 0) bad = 1;
      }
    }
    __shared__ int sh_bad;
    if (tid == 0) sh_bad = 0;
    __syncthreads();
    if (bad) atomicOr(&sh_bad, 1);
    __syncthreads();
    if (tid == 0) *flag = sh_bad ? 0 : 1;   // 1 => int64
    return;
  }
  int idx = (blockIdx.x - 1) * 256 + tid;
  const int n1 = 8 * 7 * 512;   // KI1=8
  const int n2 = 4 * 7 * 512;   // KI2=4
  if (idx < n1) {
    int fid = idx >> 3, hh = idx & 7;
    int lane = fid & 63, fg = fid >> 6;
    int kb = fg / 7, cg = fg % 7;
    int c = cg * 16 + (lane & 15);
    int k = kb * 32 + (lane >> 4) * 8 + hh;
    W1lin[idx] = (f16)((c < D_H && k < 256) ? W1[k * D_H + c] : 0.f);
  } else if (idx < n1 + n2) {
    int j = idx - n1;
    int fid = j >> 3, hh = j & 7;
    int lane = fid & 63, fg = fid >> 6;
    int kb = fg / 7, cg = fg % 7;
    int c = cg * 16 + (lane & 15);
    int k = kb * 32 + (lane >> 4) * 8 + hh;
    W2lin[j] = (f16)((c < D_H && k < D_H) ? W2[k * D_H + c] : 0.f);
  } else if (idx < n1 + n2 + 128) {
    int c = idx - (n1 + n2);
    b1p[c] = (c < D_H) ? b1[c] : 0.0f;
  } else if (idx < n1 + n2 + 256) {
    int c = idx - (n1 + n2 + 128);
    b2p[c] = (c < D_H) ? b2[c] : 0.0f;
  }
}

// ---------- MFMA GEMM body (no LDS, no barriers; A and B straight to registers) ----------
// 256 thr = 4 waves, 128 rows/block; wave w owns rows w*32..w*32+31 (2 groups of 16).
// SCALE_DINV: multiply output rows by dinv[row] (layer 2); layer 1 writes unscaled.
template<int KI, bool IN_HALF, bool SCALE_DINV>
__device__ __forceinline__ void gemm_body(
    int gb, const float* __restrict__ Af, const f16* __restrict__ Ah,
    const __half2* __restrict__ sideA,
    const f16* __restrict__ Wlin, const float* __restrict__ dinv,
    f16* __restrict__ C, __half2* __restrict__ sideC, int N) {
  int tid = threadIdx.x, wave = tid >> 6, lane = tid & 63;
  int row0 = gb * 128;
  int m = lane & 15, q = lane >> 4;
  int kf = q * 8;
  int r0 = row0 + wave * 32 + m;
  int r1 = r0 + 16;
  int rr0 = (r0 < N) ? r0 : 0;   // clamp: OOB rows compute garbage, discarded in epilogue
  int rr1 = (r1 < N) ? r1 : 0;
  const f16* wbase = Wlin + lane * 8;

  f16x8 a0[KI], a1[KI];
  #pragma unroll
  for (int kb = 0; kb < KI; ++kb) {
    if constexpr (!IN_HALF) {
      const float* p0 = &Af[(size_t)rr0 * 256 + kb * 32 + kf];
      const float* p1 = &Af[(size_t)rr1 * 256 + kb * 32 + kf];
      float4 u0 = *(const float4*)p0, u1 = *(const float4*)(p0 + 4);
      float4 w0 = *(const float4*)p1, w1 = *(const float4*)(p1 + 4);
      f16x8 t0, t1;
      t0[0] = (f16)u0.x; t0[1] = (f16)u0.y; t0[2] = (f16)u0.z; t0[3] = (f16)u0.w;
      t0[4] = (f16)u1.x; t0[5] = (f16)u1.y; t0[6] = (f16)u1.z; t0[7] = (f16)u1.w;
      t1[0] = (f16)w0.x; t1[1] = (f16)w0.y; t1[2] = (f16)w0.z; t1[3] = (f16)w0.w;
      t1[4] = (f16)w1.x; t1[5] = (f16)w1.y; t1[6] = (f16)w1.z; t1[7] = (f16)w1.w;
      a0[kb] = t0; a1[kb] = t1;
    } else {
      if (kb < KI - 1) {
        a0[kb] = *(const f16x8*)&Ah[(size_t)rr0 * RST + kb * 32 + kf];
        a1[kb] = *(const f16x8*)&Ah[(size_t)rr1 * RST + kb * 32 + kf];
      } else {
        f16x8 z0, z1;
        #pragma unroll
        for (int j = 0; j < 8; ++j) { z0[j] = (f16)0.f; z1[j] = (f16)0.f; }
        if (q == 0) {
          z0[0] = ((const f16*)sideA)[2 * rr0];
          z1[0] = ((const f16*)sideA)[2 * rr1];
        }
        a0[kb] = z0; a1[kb] = z1;
      }
    }
  }

  f32x4 acc[2][7];
  #pragma unroll
  for (int mg = 0; mg < 2; ++mg)
    #pragma unroll
    for (int cg = 0; cg < 7; ++cg)
      #pragma unroll
      for (int j = 0; j < 4; ++j) acc[mg][cg][j] = 0.f;

  #pragma unroll
  for (int kb = 0; kb < KI; ++kb) {
    #pragma unroll
    for (int cg = 0; cg < 7; ++cg) {
      f16x8 b = *(const f16x8*)&wbase[(kb * 7 + cg) * 512];
      acc[0][cg] = __builtin_amdgcn_mfma_f32_16x16x32_f16(a0[kb], b, acc[0][cg], 0, 0, 0);
      acc[1][cg] = __builtin_amdgcn_mfma_f32_16x16x32_f16(a1[kb], b, acc[1][cg], 0, 0, 0);
    }
  }

  // epilogue: C/D mapping col=lane&15, row=(lane>>4)*4+j
  int colb = m, rq = q * 4;
  #pragma unroll
  for (int mg = 0; mg < 2; ++mg) {
    #pragma unroll
    for (int j = 0; j < 4; ++j) {
      int r = row0 + wave * 32 + mg * 16 + rq + j;
      if (r >= N) continue;
      float dv = SCALE_DINV ? dinv[r] : 1.0f;
      #pragma unroll
      for (int cg = 0; cg < 7; ++cg) {
        int c = cg * 16 + colb;
        float val = SCALE_DINV ? (acc[mg][cg][j] * dv) : acc[mg][cg][j];
        if (c < 96)       C[(size_t)r * RST + c] = (f16)val;
        else if (c == 96) sideC[r] = __floats2half2_rn(val, 0.f);
      }
    }
  }
}

// ---------- Kernel B: scatter (blocks 0..nScat-1) || gemm1 (blocks nScat..) ----------
__global__ __launch_bounds__(256) void scatter_gemm1(
    const void* ei, const int* __restrict__ flag, int* __restrict__ bcur,
    unsigned int* __restrict__ bsd, long long E, int nbuck, int cap, int nScat,
    const float* __restrict__ x, const f16* __restrict__ W1lin,
    f16* __restrict__ t1, __half2* __restrict__ sideT, int N) {
  __shared__ unsigned int packs[CHUNK];
  __shared__ unsigned char bkts[CHUNK];
  __shared__ int hist[NBMAX];
  __shared__ int gpos[NBMAX];
  __shared__ int cur[NBMAX];
  int tid = threadIdx.x;
  if ((int)blockIdx.x >= nScat) {
    gemm_body<8, false, false>(blockIdx.x - nScat, x, nullptr, nullptr,
                               W1lin, nullptr, t1, sideT, N);
    return;
  }
  if (tid < NBMAX) { hist[tid] = 0; cur[tid] = 0; }
  __syncthreads();
  int f = *flag;
  long long base = (long long)blockIdx.x * CHUNK;
  int cnt = (int)((E - base < CHUNK) ? (E - base) : CHUNK);
  #pragma unroll 4
  for (int i = tid; i < cnt; i += 256) {
    long long e = base + i;
    int s = load_idx(ei, f, e);
    int d = load_idx(ei, f, E + e);
    int b = d >> 9;
    packs[i] = ((unsigned int)(d & (NPB - 1)) << 17) | (unsigned int)s;
    bkts[i] = (unsigned char)b;
    atomicAdd(&hist[b], 1);
  }
  __syncthreads();
  if (tid < nbuck) { int h = hist[tid]; if (h) gpos[tid] = atomicAdd(&bcur[tid], h); }
  __syncthreads();
  #pragma unroll 4
  for (int i = tid; i < cnt; i += 256) {
    int b = bkts[i];
    int r = atomicAdd(&cur[b], 1);
    int idx = gpos[b] + r;
    if (idx < cap) bsd[(size_t)b * cap + idx] = packs[i];   // clamp: drop on (never-hit) overflow
  }
}

// ---------- finalize: inline bucket-scan -> node histogram -> row_start + dinv -> CSR scatter ----------
__global__ __launch_bounds__(256) void bucket_finalize(
    const unsigned int* __restrict__ bsd, const int* __restrict__ bcur,
    int* __restrict__ row_start, float* __restrict__ dinv,
    int* __restrict__ csr_src, int N, int cap, int nbuck) {
  __shared__ int sc[256];
  __shared__ int h[NPB];
  __shared__ int rs[NPB];
  __shared__ int cur[NPB];
  __shared__ int wsum[4];
  int b = blockIdx.x, tid = threadIdx.x;
  int lane = tid & 63, wid = tid >> 6;
  int v = (tid < nbuck) ? min(bcur[tid], cap) : 0;
  sc[tid] = v;
  h[2 * tid] = 0; h[2 * tid + 1] = 0;
  cur[2 * tid] = 0; cur[2 * tid + 1] = 0;
  __syncthreads();
  for (int o = 1; o < 256; o <<= 1) {
    int a = (tid >= o) ? sc[tid - o] : 0;
    __syncthreads();
    sc[tid] += a;
    __syncthreads();
  }
  int cnt = min(bcur[b], cap);
  int base = sc[b] - cnt;             // exclusive prefix for this bucket
  if (b == 0 && tid == 0) row_start[N] = sc[255];
  int d0 = b * cap;
  for (int i = tid; i < cnt; i += 256) atomicAdd(&h[bsd[d0 + i] >> 17], 1);
  __syncthreads();
  int a0 = h[2 * tid], a1 = h[2 * tid + 1];
  int tsum = a0 + a1;
  int incl = tsum;
  #pragma unroll
  for (int off = 1; off < 64; off <<= 1) {
    int n = __shfl_up(incl, off, 64);
    if (lane >= off) incl += n;
  }
  if (lane == 63) wsum[wid] = incl;
  __syncthreads();
  int woff = 0;
  for (int k = 0; k < wid; ++k) woff += wsum[k];
  int excl = woff + incl - tsum + base;
  rs[2 * tid] = excl;
  rs[2 * tid + 1] = excl + a0;
  int node0 = b * NPB;
  int n0 = node0 + 2 * tid, n1 = node0 + 2 * tid + 1;
  if (n0 < N) { row_start[n0] = excl;      dinv[n0] = rsqrtf((float)(a0 + 1)); }
  if (n1 < N) { row_start[n1] = excl + a0; dinv[n1] = rsqrtf((float)(a1 + 1)); }
  __syncthreads();
  for (int i = tid; i < cnt; i += 256) {
    unsigned int p = bsd[d0 + i];
    int r = p >> 17;
    int s = (int)(p & 0x1FFFFu);
    int rel = atomicAdd(&cur[r], 1);
    csr_src[rs[r] + rel] = s;
  }
}

// ---------- standalone gemm2 (folds dinv into t2; runs after finalize) ----------
__global__ __launch_bounds__(256) void mfma_gemm2(
    const f16* __restrict__ Ah, const __half2* __restrict__ sideA,
    const f16* __restrict__ Wlin, const float* __restrict__ dinv,
    f16* __restrict__ C, __half2* __restrict__ sideC, int N) {
  gemm_body<4, true, true>(blockIdx.x, nullptr, Ah, sideA, Wlin, dinv, C, sideC, N);
}

// ---------- CSR aggregation: one wave per destination node, fp16 gather, f32 accum ----------
// SRC_SCALE: t rows are UNSCALED; multiply each gathered row by dinv[src] (L2-resident array).
template<bool OUT_HALF, bool DO_RELU, bool SRC_SCALE>
__global__ __launch_bounds__(256) void agg_kernel(
    const __half* __restrict__ t, const __half2* __restrict__ side,
    const int* __restrict__ csr_src, const int* __restrict__ row_start,
    const float* __restrict__ dinv, const float* __restrict__ bias,
    void* __restrict__ outp, __half2* __restrict__ side_out, int N) {
  int lane = threadIdx.x & 63;
  int node = blockIdx.x * (blockDim.x >> 6) + (threadIdx.x >> 6);
  if (node >= N || lane >= 49) return;
  const char* gbase = (lane < 48) ? (const char*)t + lane * 4 : (const char*)side;
  unsigned gscale = (lane < 48) ? (unsigned)(RST * 2) : 4u;
  auto GATHER = [&](int j) -> float2 {
    return __half22float2(*(const __half2*)(gbase + (size_t)((unsigned)j * gscale)));
  };
  int s = row_start[node], epd = row_start[node + 1];
  float di = dinv[node];
  float2 v = GATHER(node);           // self term
  float ax, ay;
  if (SRC_SCALE) { ax = di * v.x; ay = di * v.y; }
  else           { ax = v.x;      ay = v.y; }
  int e = s;
  while ((e & 3) && e < epd) {
    int j = csr_src[e];
    float2 u = GATHER(j);
    if (SRC_SCALE) { float w = dinv[j]; ax = fmaf(w, u.x, ax); ay = fmaf(w, u.y, ay); }
    else           { ax += u.x; ay += u.y; }
    ++e;
  }
  for (; e + 8 <= epd; e += 8) {
    int4 q0 = *(const int4*)(csr_src + e);
    int4 q1 = *(const int4*)(csr_src + e + 4);
    float2 u0 = GATHER(q0.x), u1 = GATHER(q0.y), u2 = GATHER(q0.z), u3 = GATHER(q0.w);
    float2 u4 = GATHER(q1.x), u5 = GATHER(q1.y), u6 = GATHER(q1.z), u7 = GATHER(q1.w);
    if (SRC_SCALE) {
      float w0 = dinv[q0.x], w1 = dinv[q0.y], w2 = dinv[q0.z], w3 = dinv[q0.w];
      float w4 = dinv[q1.x], w5 = dinv[q1.y], w6 = dinv[q1.z], w7 = dinv[q1.w];
      ax += (fmaf(w0, u0.x, w1 * u1.x) + fmaf(w2, u2.x, w3 * u3.x)) +
            (fmaf(w4, u4.x, w5 * u5.x) + fmaf(w6, u6.x, w7 * u7.x));
      ay += (fmaf(w0, u0.y, w1 * u1.y) + fmaf(w2, u2.y, w3 * u3.y)) +
            (fmaf(w4, u4.y, w5 * u5.y) + fmaf(w6, u6.y, w7 * u7.y));
    } else {
      ax += ((u0.x + u1.x) + (u2.x + u3.x)) + ((u4.x + u5.x) + (u6.x + u7.x));
      ay += ((u0.y + u1.y) + (u2.y + u3.y)) + ((u4.y + u5.y) + (u6.y + u7.y));
    }
  }
  if (e + 4 <= epd) {
    int4 q0 = *(const int4*)(csr_src + e);
    float2 u0 = GATHER(q0.x), u1 = GATHER(q0.y), u2 = GATHER(q0.z), u3 = GATHER(q0.w);
    if (SRC_SCALE) {
      float w0 = dinv[q0.x], w1 = dinv[q0.y], w2 = dinv[q0.z], w3 = dinv[q0.w];
      ax += fmaf(w0, u0.x, w1 * u1.x) + fmaf(w2, u2.x, w3 * u3.x);
      ay += fmaf(w0, u0.y, w1 * u1.y) + fmaf(w2, u2.y, w3 * u3.y);
    } else {
      ax += (u0.x + u1.x) + (u2.x + u3.x);
      ay += (u0.y + u1.y) + (u2.y + u3.y);
    }
    e += 4;
  }
  for (; e < epd; ++e) {
    int j = csr_src[e];
    float2 u = GATHER(j);
    if (SRC_SCALE) { float w = dinv[j]; ax = fmaf(w, u.x, ax); ay = fmaf(w, u.y, ay); }
    else           { ax += u.x; ay += u.y; }
  }
  int c0 = 2 * lane;                 // lane 48 -> c0 = 96
  ax = ax * di + bias[c0];
  ay = ay * di + bias[c0 + 1];
  if (DO_RELU) { ax = fmaxf(ax, 0.f); ay = fmaxf(ay, 0.f); }
  if (OUT_HALF) {
    if (lane < 48) ((__half2*)((__half*)outp + (size_t)node * RST))[lane] = __floats2half2_rn(ax, ay);
    else           side_out[node] = __floats2half2_rn(ax, 0.f);
  } else {
    float* o = (float*)outp + (size_t)node * D_H;
    if (lane < 48) { o[c0] = ax; o[c0 + 1] = ay; }
    else           o[96] = ax;
  }
}

// ---------- launch ----------
extern "C" void kernel_launch(void* const* d_in, const int* in_sizes, int n_in,
                              void* d_out, int out_size, void* d_ws, size_t ws_size,
                              hipStream_t stream) {
  const float* x  = (const float*)d_in[0];
  const void*  ei = d_in[1];
  const float* W1 = (const float*)d_in[2];
  const float* b1 = (const float*)d_in[3];
  const float* W2 = (const float*)d_in[4];
  const float* b2 = (const float*)d_in[5];
  int N = in_sizes[0] / D_IN;
  long long E = (long long)in_sizes[1] / 2;
  int nbuck = (N + NPB - 1) / NPB;
  int cap = (int)(E / nbuck) + 8192;   // uniform-random slack >> 6 sigma

  char* base = (char*)d_ws;
  size_t off = 0;
  auto alloc = [&](size_t bytes) -> void* {
    void* p = base + off;
    off = (off + bytes + 255) & ~(size_t)255;
    return p;
  };
  int*    flag      = (int*)alloc(4);
  float*  dinv      = (float*)alloc((size_t)N * 4);
  int*    row_start = (int*)alloc((size_t)(N + 1) * 4);
  int*    bcur      = (int*)alloc((size_t)(nbuck + 1) * 4);
  int*    csr_src   = (int*)alloc((size_t)E * 4);
  unsigned int* bsd = (unsigned int*)alloc((size_t)nbuck * cap * 4);
  f16*    W1lin     = (f16*)alloc((size_t)8 * 7 * 512 * 2);
  f16*    W2lin     = (f16*)alloc((size_t)4 * 7 * 512 * 2);
  float*  b1p       = (float*)alloc(128 * 4);
  float*  b2p       = (float*)alloc(128 * 4);
  f16*    t1        = (f16*)alloc((size_t)N * RST * 2 + 256);
  __half2* sideT    = (__half2*)alloc((size_t)N * 4 + 256);
  f16*    h1        = (f16*)alloc((size_t)N * RST * 2 + 256);
  __half2* sideH    = (__half2*)alloc((size_t)N * 4 + 256);

  const int prepTot = 8 * 7 * 512 + 4 * 7 * 512 + 256;
  int gPrep = (prepTot + 255) / 256;
  int nScat = (int)((E + CHUNK - 1) / CHUNK);
  int gGemm = (N + 127) / 128;

  detect_prep<<<1 + gPrep, 256, 0, stream>>>(
      ei, E, flag, bcur, nbuck, W1, b1, W2, b2, W1lin, W2lin, b1p, b2p);
  scatter_gemm1<<<nScat + gGemm, 256, 0, stream>>>(
      ei, flag, bcur, bsd, E, nbuck, cap, nScat, x, W1lin, t1, sideT, N);
  bucket_finalize<<<nbuck, 256, 0, stream>>>(
      bsd, bcur, row_start, dinv, csr_src, N, cap, nbuck);
  agg_kernel<true, true, true><<<(N + 3) / 4, 256, 0, stream>>>(
      (const __half*)t1, sideT, csr_src, row_start, dinv, b1p, h1, sideH, N);
  mfma_gemm2<<<gGemm, 256, 0, stream>>>(h1, sideH, W2lin, dinv, t1, sideT, N);
  agg_kernel<false, false, false><<<(N + 3) / 4, 256, 0, stream>>>(
      (const __half*)t1, sideT, csr_src, row_start, dinv, b2p, d_out, nullptr, N);
}